// Round 3
// baseline (271.632 us; speedup 1.0000x reference)
//
#include <hip/hip_runtime.h>

#define NROWS 8192
#define KD    128
#define SQK1C 4.5398163f   /* sqrt(log2(e)/0.07); product of two scaled ops gives K1C*sim */

typedef __bf16 bf16x8 __attribute__((ext_vector_type(8)));
typedef float  f32x16 __attribute__((ext_vector_type(16)));

typedef __attribute__((address_space(1))) void* gas_ptr;
typedef __attribute__((address_space(3))) void* las_ptr;

__device__ __forceinline__ unsigned short f2bf(float x) {
  unsigned int u = __builtin_bit_cast(unsigned int, x);
  unsigned int r = (u + 0x7FFFu + ((u >> 16) & 1u)) >> 16;  // RNE
  return (unsigned short)r;
}

// Convert fp32 inputs to bf16 scaled by sqrt(K1C); zero the 4 sum arrays.
__global__ __launch_bounds__(256) void prep_kernel(const float4* __restrict__ F4,
                                                   const float4* __restrict__ M4,
                                                   ushort4* __restrict__ Fb4,
                                                   ushort4* __restrict__ Mb4,
                                                   float* __restrict__ sums) {
  int i = blockIdx.x * 256 + threadIdx.x;
  float4 f = F4[i];
  float4 m = M4[i];
  ushort4 fo, mo;
  fo.x = f2bf(f.x * SQK1C); fo.y = f2bf(f.y * SQK1C);
  fo.z = f2bf(f.z * SQK1C); fo.w = f2bf(f.w * SQK1C);
  mo.x = f2bf(m.x * SQK1C); mo.y = f2bf(m.y * SQK1C);
  mo.z = f2bf(m.z * SQK1C); mo.w = f2bf(m.w * SQK1C);
  Fb4[i] = fo;
  Mb4[i] = mo;
  if (i < 4 * NROWS) sums[i] = 0.0f;
}

// ---------------- FM kernel: rowsum -> Spos_f, colsum -> Spos_m ----------------
// 4 waves (2x2), wave tile 64x64, normal orientation (lane = out-col -> colsum lane-local).
__global__ __launch_bounds__(256, 2) void gemm_fm(const unsigned short* __restrict__ Fb,
                                                  const unsigned short* __restrict__ Mb,
                                                  float* __restrict__ sums) {
  __shared__ __align__(16) unsigned short lds[2][128 * 128];  // 2 x 32KB
  const int bx = blockIdx.x;   // 0..7 col split (1024 cols)
  const int by = blockIdx.y;   // 0..63 row block (128 rows)
  const int tid = threadIdx.x, lane = tid & 63, wave = tid >> 6;
  const int wr = wave >> 1, wc = wave & 1;
  const int l31 = lane & 31, lh = lane >> 5;
  float* rowsum = sums;          // Spos_f
  float* colsum = sums + NROWS;  // Spos_m

  auto stage = [&](void* dst, const unsigned short* src) {
    #pragma unroll
    for (int i = 0; i < 8; ++i) {
      const int lin = tid * 16 + i * 4096;
      const int row = lin >> 8;
      const int sbc = (lin & 255) ^ ((row & 7) << 4);
      __builtin_amdgcn_global_load_lds((gas_ptr)((const char*)src + row * 256 + sbc),
                                       (las_ptr)((char*)dst + lin), 16, 0, 0);
    }
  };

  stage(lds[0], Fb + (size_t)by * 128 * KD);
  stage(lds[1], Mb + (size_t)bx * 1024 * KD);
  __syncthreads();

  bf16x8 af[2][8];  // A rows (64 per wave) in regs
  #pragma unroll
  for (int mb = 0; mb < 2; ++mb) {
    const int row = wr * 64 + mb * 32 + l31;
    const char* ab = (const char*)lds[0] + row * 256;
    const int sw = (row & 7) << 4;
    #pragma unroll
    for (int ks = 0; ks < 8; ++ks)
      af[mb][ks] = *(const bf16x8*)(ab + ((ks * 32 + lh * 16) ^ sw));
  }
  __syncthreads();  // af reads drained before t=0 stages into lds[0]

  float rowacc[32];
  #pragma unroll
  for (int i = 0; i < 32; ++i) rowacc[i] = 0.f;

  const unsigned short* Bbase = Mb + (size_t)bx * 1024 * KD;
  const int prow0 = wc * 64 + l31;
  const int psw = (prow0 & 7) << 4;

  #pragma unroll
  for (int t = 0; t < 8; ++t) {
    if (t < 7) stage(lds[t & 1], Bbase + (size_t)(t + 1) * 128 * KD);
    const char* bb = (const char*)lds[(t + 1) & 1];
    f32x16 acc[2][2];
    __builtin_amdgcn_s_setprio(1);
    #pragma unroll
    for (int nb = 0; nb < 2; ++nb) {
      const char* pb = bb + (prow0 + nb * 32) * 256;
      bf16x8 bp[8];
      #pragma unroll
      for (int ks = 0; ks < 8; ++ks)
        bp[ks] = *(const bf16x8*)(pb + ((ks * 32 + lh * 16) ^ psw));
      #pragma unroll
      for (int ks = 0; ks < 8; ++ks) {
        acc[0][nb] = __builtin_amdgcn_mfma_f32_32x32x16_bf16(af[0][ks], bp[ks],
                        ks ? acc[0][nb] : (f32x16){}, 0, 0, 0);
        acc[1][nb] = __builtin_amdgcn_mfma_f32_32x32x16_bf16(af[1][ks], bp[ks],
                        ks ? acc[1][nb] : (f32x16){}, 0, 0, 0);
      }
    }
    __builtin_amdgcn_s_setprio(0);

    // epilogue: v = exp2(acc); rowacc per (mb,r); colacc lane-local per nb.
    float ca0 = 0.f, ca1 = 0.f;
    #pragma unroll
    for (int mb = 0; mb < 2; ++mb) {
      #pragma unroll
      for (int r = 0; r < 16; ++r) {
        float v0 = __builtin_amdgcn_exp2f(acc[mb][0][r]);
        float v1 = __builtin_amdgcn_exp2f(acc[mb][1][r]);
        rowacc[mb * 16 + r] += v0 + v1;
        ca0 += v0; ca1 += v1;
      }
    }
    ca0 += __shfl_xor(ca0, 32);
    ca1 += __shfl_xor(ca1, 32);
    if (lh == 0) {
      float* cp = colsum + bx * 1024 + t * 128 + wc * 64 + l31;
      unsafeAtomicAdd(cp, ca0);
      unsafeAtomicAdd(cp + 32, ca1);
    }
    __syncthreads();
  }

  // Final rowsum flush: butterfly over the 32-lane col group, 2 lanes do atomics.
  #pragma unroll
  for (int i = 0; i < 32; ++i) {
    float v = rowacc[i];
    v += __shfl_xor(v, 1);
    v += __shfl_xor(v, 2);
    v += __shfl_xor(v, 4);
    v += __shfl_xor(v, 8);
    v += __shfl_xor(v, 16);
    if (l31 == 0) {
      const int r = i & 15, mb = i >> 4;
      unsafeAtomicAdd(rowsum + by * 128 + wr * 64 + mb * 32 +
                          (r & 3) + 8 * (r >> 2) + 4 * lh, v);
    }
  }
}

// ---------------- symmetric kernel (FF / MM): rowsum only, diag masked ----------------
// Swapped operands: mfma(B_panel, A_frag) -> lane = out-ROW; rowsum lane-local (2 regs).
// T15: double-buffered acc, epilogue(t-1) overlaps MFMA(t).
__global__ __launch_bounds__(256, 2) void gemm_sym(const unsigned short* __restrict__ Fb,
                                                   const unsigned short* __restrict__ Mb,
                                                   float* __restrict__ sums) {
  __shared__ __align__(16) unsigned short lds[2][128 * 128];
  const int bx = blockIdx.x, by = blockIdx.y;
  const unsigned short* X = blockIdx.z ? Mb : Fb;
  float* rowsum = sums + (blockIdx.z ? 3 : 2) * NROWS;

  const int tid = threadIdx.x, lane = tid & 63, wave = tid >> 6;
  const int wr = wave >> 1, wc = wave & 1;
  const int l31 = lane & 31, lh = lane >> 5;

  auto stage = [&](void* dst, const unsigned short* src) {
    #pragma unroll
    for (int i = 0; i < 8; ++i) {
      const int lin = tid * 16 + i * 4096;
      const int row = lin >> 8;
      const int sbc = (lin & 255) ^ ((row & 7) << 4);
      __builtin_amdgcn_global_load_lds((gas_ptr)((const char*)src + row * 256 + sbc),
                                       (las_ptr)((char*)dst + lin), 16, 0, 0);
    }
  };

  stage(lds[0], X + (size_t)by * 128 * KD);
  stage(lds[1], X + (size_t)bx * 1024 * KD);
  __syncthreads();

  bf16x8 af[2][8];  // our rows (swapped: B-operand)
  #pragma unroll
  for (int jb = 0; jb < 2; ++jb) {
    const int row = wr * 64 + jb * 32 + l31;
    const char* ab = (const char*)lds[0] + row * 256;
    const int sw = (row & 7) << 4;
    #pragma unroll
    for (int ks = 0; ks < 8; ++ks)
      af[jb][ks] = *(const bf16x8*)(ab + ((ks * 32 + lh * 16) ^ sw));
  }
  __syncthreads();

  float ra0 = 0.f, ra1 = 0.f;   // lane-local rowsums (jb = 0,1)
  const unsigned short* Bbase = X + (size_t)bx * 1024 * KD;
  const int prow0 = wc * 64 + l31;
  const int psw = (prow0 & 7) << 4;
  const int Rb0 = by * 128 + wr * 64;             // wave row base
  const int pat = (0 & 3);                        // placeholder (computed per r below)

  f32x16 acc[2][2][2];  // [t&1][jb][ib]

  // epilogue of tile tp using acc[tp&1]
  auto epi = [&](int tp, f32x16 (&ac)[2][2]) {
    const int Cb0 = bx * 1024 + tp * 128 + wc * 64;
    #pragma unroll
    for (int jb = 0; jb < 2; ++jb) {
      const int Rb = Rb0 + jb * 32;
      float s = 0.f;
      #pragma unroll
      for (int ib = 0; ib < 2; ++ib) {
        const bool dg = (Rb == Cb0 + ib * 32);
        float p[4];
        #pragma unroll
        for (int q = 0; q < 4; ++q) {
          float v0 = __builtin_amdgcn_exp2f(ac[jb][ib][q * 4 + 0]);
          float v1 = __builtin_amdgcn_exp2f(ac[jb][ib][q * 4 + 1]);
          float v2 = __builtin_amdgcn_exp2f(ac[jb][ib][q * 4 + 2]);
          float v3 = __builtin_amdgcn_exp2f(ac[jb][ib][q * 4 + 3]);
          if (dg) {
            // mask out-row==out-col: col = (r&3)+8*(r>>2)+4*lh, r = q*4+j
            #pragma unroll
            for (int j = 0; j < 4; ++j) {
              if ((j + 8 * q + 4 * lh) == l31) {
                if (j == 0) v0 = 0.f;
                if (j == 1) v1 = 0.f;
                if (j == 2) v2 = 0.f;
                if (j == 3) v3 = 0.f;
              }
            }
          }
          p[q] = (v0 + v1) + (v2 + v3);
        }
        s += (p[0] + p[1]) + (p[2] + p[3]);
      }
      if (jb == 0) ra0 += s; else ra1 += s;
    }
  };

  #pragma unroll
  for (int t = 0; t < 8; ++t) {
    if (t < 7) stage(lds[t & 1], Bbase + (size_t)(t + 1) * 128 * KD);
    const char* bb = (const char*)lds[(t + 1) & 1];
    __builtin_amdgcn_s_setprio(1);
    #pragma unroll
    for (int ib = 0; ib < 2; ++ib) {
      const char* pb = bb + (prow0 + ib * 32) * 256;
      bf16x8 bp[8];
      #pragma unroll
      for (int ks = 0; ks < 8; ++ks)
        bp[ks] = *(const bf16x8*)(pb + ((ks * 32 + lh * 16) ^ psw));
      #pragma unroll
      for (int ks = 0; ks < 8; ++ks) {
        acc[t & 1][0][ib] = __builtin_amdgcn_mfma_f32_32x32x16_bf16(bp[ks], af[0][ks],
                               ks ? acc[t & 1][0][ib] : (f32x16){}, 0, 0, 0);
        acc[t & 1][1][ib] = __builtin_amdgcn_mfma_f32_32x32x16_bf16(bp[ks], af[1][ks],
                               ks ? acc[t & 1][1][ib] : (f32x16){}, 0, 0, 0);
      }
    }
    __builtin_amdgcn_s_setprio(0);
    if (t > 0) epi(t - 1, acc[(t - 1) & 1]);  // overlaps with MFMA(t) in flight
    __syncthreads();
  }
  epi(7, acc[1]);

  // lane-local rowsum flush: combine lh halves, 32 lanes atomic.
  ra0 += __shfl_xor(ra0, 32);
  ra1 += __shfl_xor(ra1, 32);
  if (lh == 0) {
    unsafeAtomicAdd(rowsum + Rb0 + l31, ra0);
    unsafeAtomicAdd(rowsum + Rb0 + 32 + l31, ra1);
  }
  (void)pat;
}

// loss = 1.5*mean(log1p(Sneg_f/Spos_f)) + 0.5*mean(log1p(Sneg_m/Spos_m))
// (uniform 2^{-K1C} scale cancels in the ratios)
__global__ __launch_bounds__(1024) void loss_kernel(const float* __restrict__ sums,
                                                    float* __restrict__ out) {
  const float* Spf = sums;
  const float* Spm = sums + NROWS;
  const float* Snf = sums + 2 * NROWS;
  const float* Snm = sums + 3 * NROWS;
  float accf = 0.f, accm = 0.f;
  for (int i = threadIdx.x; i < NROWS; i += 1024) {
    accf += log1pf(Snf[i] / Spf[i]);
    accm += log1pf(Snm[i] / Spm[i]);
  }
  float v = 1.5f * accf + 0.5f * accm;
  #pragma unroll
  for (int s = 1; s < 64; s <<= 1) v += __shfl_xor(v, s);
  __shared__ float red[16];
  if ((threadIdx.x & 63) == 0) red[threadIdx.x >> 6] = v;
  __syncthreads();
  if (threadIdx.x == 0) {
    float s = 0.f;
    #pragma unroll
    for (int i = 0; i < 16; ++i) s += red[i];
    out[0] = s * (1.0f / NROWS);
  }
}

extern "C" void kernel_launch(void* const* d_in, const int* in_sizes, int n_in,
                              void* d_out, int out_size, void* d_ws, size_t ws_size,
                              hipStream_t stream) {
  (void)in_sizes; (void)n_in; (void)out_size; (void)ws_size;
  const float* F = (const float*)d_in[0];
  const float* M = (const float*)d_in[1];
  float* out = (float*)d_out;

  float* sums = (float*)d_ws;
  unsigned short* Fb = (unsigned short*)((char*)d_ws + 4 * NROWS * sizeof(float));
  unsigned short* Mb = Fb + (size_t)NROWS * KD;

  prep_kernel<<<dim3(NROWS * KD / 4 / 256), dim3(256), 0, stream>>>(
      (const float4*)F, (const float4*)M, (ushort4*)Fb, (ushort4*)Mb, sums);
  gemm_fm<<<dim3(8, 64), dim3(256), 0, stream>>>(Fb, Mb, sums);
  gemm_sym<<<dim3(8, 64, 2), dim3(256), 0, stream>>>(Fb, Mb, sums);
  loss_kernel<<<dim3(1), dim3(1024), 0, stream>>>(sums, out);
}

// Round 4
// 151.562 us; speedup vs baseline: 1.7922x; 1.7922x over previous
//
#include <hip/hip_runtime.h>

#define NROWS 8192
#define KD    128
#define SQK1C 4.5398163f   /* sqrt(log2(e)/0.07); scaled ops make MFMA emit K1C*sim */

typedef __bf16 bf16x8 __attribute__((ext_vector_type(8)));
typedef float  f32x4  __attribute__((ext_vector_type(4)));

typedef __attribute__((address_space(1))) void* gas_ptr;
typedef __attribute__((address_space(3))) void* las_ptr;

__device__ __forceinline__ unsigned short f2bf(float x) {
  unsigned int u = __builtin_bit_cast(unsigned int, x);
  unsigned int r = (u + 0x7FFFu + ((u >> 16) & 1u)) >> 16;  // RNE
  return (unsigned short)r;
}

// fp32 -> bf16 scaled by sqrt(K1C); zero the 4 sum arrays.
__global__ __launch_bounds__(256) void prep_kernel(const float4* __restrict__ F4,
                                                   const float4* __restrict__ M4,
                                                   ushort4* __restrict__ Fb4,
                                                   ushort4* __restrict__ Mb4,
                                                   float* __restrict__ sums) {
  int i = blockIdx.x * 256 + threadIdx.x;
  float4 f = F4[i];
  float4 m = M4[i];
  ushort4 fo, mo;
  fo.x = f2bf(f.x * SQK1C); fo.y = f2bf(f.y * SQK1C);
  fo.z = f2bf(f.z * SQK1C); fo.w = f2bf(f.w * SQK1C);
  mo.x = f2bf(m.x * SQK1C); mo.y = f2bf(m.y * SQK1C);
  mo.z = f2bf(m.z * SQK1C); mo.w = f2bf(m.w * SQK1C);
  Fb4[i] = fo;
  Mb4[i] = mo;
  if (i < 4 * NROWS) sums[i] = 0.0f;
}

// z=0: FM (rowsum->Spos_f, colsum->Spos_m). z=1: FF (rowsum->Sneg_f, diag masked).
// z=2: MM (rowsum->Sneg_m, diag masked).
// 4 waves (2 wr x 2 wc). Block strip 128 rows x 1024 cols; 16 chunks of 64 cols.
// A (128x128) in regs per wave (64 rows); B chunks double-buffered 2x16KB LDS.
// LDS = 32KB -> 4 blocks/CU; VGPR capped 128 by launch_bounds(256,4).
__global__ __launch_bounds__(256, 4) void gemm_kernel(const unsigned short* __restrict__ Fb,
                                                      const unsigned short* __restrict__ Mb,
                                                      float* __restrict__ sums) {
  __shared__ __align__(16) unsigned short lds[2][64 * KD];  // 2 x 16KB (A-stage uses all 32KB)

  const int bx = blockIdx.x;   // 0..7   col strip (1024)
  const int by = blockIdx.y;   // 0..63  row block (128)
  const int z  = blockIdx.z;   // 0..2

  const unsigned short* A;
  const unsigned short* B;
  float* rowsum;
  float* colsum = nullptr;
  if (z == 0)      { A = Fb; B = Mb; rowsum = sums;             colsum = sums + NROWS; }
  else if (z == 1) { A = Fb; B = Fb; rowsum = sums + 2 * NROWS; }
  else             { A = Mb; B = Mb; rowsum = sums + 3 * NROWS; }

  const int tid  = threadIdx.x;
  const int lane = tid & 63;
  const int wave = tid >> 6;          // 0..3
  const int wr = wave >> 1, wc = wave & 1;
  const int l15 = lane & 15, l4 = lane >> 4;

  // Stage one 16KB B-chunk (64 rows x 256B). Linear LDS dest; source pre-XORed (rule 21).
  auto stageB = [&](void* dst, const unsigned short* src) {
    #pragma unroll
    for (int i = 0; i < 4; ++i) {
      const int lin = tid * 16 + i * 4096;
      const int row = lin >> 8;
      const int sbc = (lin & 255) ^ ((row & 7) << 4);
      __builtin_amdgcn_global_load_lds((gas_ptr)((const char*)src + row * 256 + sbc),
                                       (las_ptr)((char*)dst + lin), 16, 0, 0);
    }
  };

  // ---- A strip (32KB) through LDS into regs
  {
    const unsigned short* Abase = A + (size_t)by * 128 * KD;
    #pragma unroll
    for (int i = 0; i < 8; ++i) {
      const int lin = tid * 16 + i * 4096;
      const int row = lin >> 8;
      const int sbc = (lin & 255) ^ ((row & 7) << 4);
      __builtin_amdgcn_global_load_lds((gas_ptr)((const char*)Abase + row * 256 + sbc),
                                       (las_ptr)((char*)lds + lin), 16, 0, 0);
    }
  }
  __syncthreads();

  bf16x8 af[4][4];   // 64 rows x K128 per wave
  #pragma unroll
  for (int m = 0; m < 4; ++m) {
    const int row = wr * 64 + m * 16 + l15;
    const char* ab = (const char*)lds + row * 256;
    const int sw = (row & 7) << 4;
    #pragma unroll
    for (int k = 0; k < 4; ++k)
      af[m][k] = *(const bf16x8*)(ab + ((k * 64 + l4 * 16) ^ sw));
  }
  __syncthreads();   // all waves done with A before B chunk 0 overwrites

  float rowacc[16];
  #pragma unroll
  for (int i = 0; i < 16; ++i) rowacc[i] = 0.f;

  const unsigned short* Bbase = B + (size_t)bx * 1024 * KD;
  stageB(lds[0], Bbase);
  stageB(lds[1], Bbase + 64 * KD);
  __syncthreads();

  const int brow0 = wc * 32 + l15;          // n=0 B-row (out col); n=1 adds 16
  const int bsw   = (brow0 & 7) << 4;       // (brow0+16)&7 == brow0&7

  for (int t = 0; t < 16; ++t) {
    const char* bb = (const char*)lds[t & 1];
    const char* pb0 = bb + brow0 * 256;

    f32x4 acc[4][2] = {};
    __builtin_amdgcn_s_setprio(1);
    #pragma unroll
    for (int k = 0; k < 4; ++k) {
      const int c = (k * 64 + l4 * 16) ^ bsw;
      bf16x8 b0 = *(const bf16x8*)(pb0 + c);
      bf16x8 b1 = *(const bf16x8*)(pb0 + 16 * 256 + c);
      #pragma unroll
      for (int m = 0; m < 4; ++m) {
        acc[m][0] = __builtin_amdgcn_mfma_f32_16x16x32_bf16(af[m][k], b0, acc[m][0], 0, 0, 0);
        acc[m][1] = __builtin_amdgcn_mfma_f32_16x16x32_bf16(af[m][k], b1, acc[m][1], 0, 0, 0);
      }
    }
    __builtin_amdgcn_s_setprio(0);

    // Epilogue: v = exp2(K1C*sim); rowacc in regs; colsum (z==0) lane-local + atomic.
    const bool diag = (z > 0) && ((((bx << 4) + t) >> 1) == by);
    if (z == 0) {
      float ca0 = 0.f, ca1 = 0.f;
      #pragma unroll
      for (int m = 0; m < 4; ++m) {
        #pragma unroll
        for (int j = 0; j < 4; ++j) {
          float v0 = __builtin_amdgcn_exp2f(acc[m][0][j]);
          float v1 = __builtin_amdgcn_exp2f(acc[m][1][j]);
          rowacc[m * 4 + j] += v0 + v1;
          ca0 += v0; ca1 += v1;
        }
      }
      ca0 += __shfl_xor(ca0, 16);
      ca0 += __shfl_xor(ca0, 32);
      ca1 += __shfl_xor(ca1, 16);
      ca1 += __shfl_xor(ca1, 32);
      if (l4 == 0) {
        float* cp = colsum + bx * 1024 + t * 64 + wc * 32 + l15;
        unsafeAtomicAdd(cp, ca0);
        unsafeAtomicAdd(cp + 16, ca1);
      }
    } else {
      #pragma unroll
      for (int m = 0; m < 4; ++m) {
        #pragma unroll
        for (int j = 0; j < 4; ++j) {
          float v0 = __builtin_amdgcn_exp2f(acc[m][0][j]);
          float v1 = __builtin_amdgcn_exp2f(acc[m][1][j]);
          if (diag) {
            const int grow = by * 128 + wr * 64 + m * 16 + l4 * 4 + j;
            const int gcol = bx * 1024 + t * 64 + wc * 32 + l15;
            if (grow == gcol)      v0 = 0.f;
            if (grow == gcol + 16) v1 = 0.f;
          }
          rowacc[m * 4 + j] += v0 + v1;
        }
      }
    }
    __syncthreads();                    // drains vmcnt+lgkm; buffer t&1 free to re-stage
    if (t < 14) stageB(lds[t & 1], Bbase + (size_t)(t + 2) * 64 * KD);
  }

  // rowsum flush: butterfly over l15 (cols), 4 lanes/wave do the atomics.
  #pragma unroll
  for (int i = 0; i < 16; ++i) {
    float v = rowacc[i];
    v += __shfl_xor(v, 1);
    v += __shfl_xor(v, 2);
    v += __shfl_xor(v, 4);
    v += __shfl_xor(v, 8);
    rowacc[i] = v;
  }
  if (l15 == 0) {
    const int rbase = by * 128 + wr * 64 + l4 * 4;
    #pragma unroll
    for (int i = 0; i < 16; ++i)
      unsafeAtomicAdd(rowsum + rbase + (i >> 2) * 16 + (i & 3), rowacc[i]);
  }
}

// loss = 1.5*mean(log1p(Sneg_f/Spos_f)) + 0.5*mean(log1p(Sneg_m/Spos_m))
// (uniform 2^{-K1C} factor cancels in the ratios)
__global__ __launch_bounds__(1024) void loss_kernel(const float* __restrict__ sums,
                                                    float* __restrict__ out) {
  const float* Spf = sums;
  const float* Spm = sums + NROWS;
  const float* Snf = sums + 2 * NROWS;
  const float* Snm = sums + 3 * NROWS;
  float accf = 0.f, accm = 0.f;
  for (int i = threadIdx.x; i < NROWS; i += 1024) {
    accf += log1pf(Snf[i] / Spf[i]);
    accm += log1pf(Snm[i] / Spm[i]);
  }
  float v = 1.5f * accf + 0.5f * accm;
  #pragma unroll
  for (int s = 1; s < 64; s <<= 1) v += __shfl_xor(v, s);
  __shared__ float red[16];
  if ((threadIdx.x & 63) == 0) red[threadIdx.x >> 6] = v;
  __syncthreads();
  if (threadIdx.x == 0) {
    float s = 0.f;
    #pragma unroll
    for (int i = 0; i < 16; ++i) s += red[i];
    out[0] = s * (1.0f / NROWS);
  }
}

extern "C" void kernel_launch(void* const* d_in, const int* in_sizes, int n_in,
                              void* d_out, int out_size, void* d_ws, size_t ws_size,
                              hipStream_t stream) {
  (void)in_sizes; (void)n_in; (void)out_size; (void)ws_size;
  const float* F = (const float*)d_in[0];
  const float* M = (const float*)d_in[1];
  float* out = (float*)d_out;

  float* sums = (float*)d_ws;
  unsigned short* Fb = (unsigned short*)((char*)d_ws + 4 * NROWS * sizeof(float));
  unsigned short* Mb = Fb + (size_t)NROWS * KD;

  prep_kernel<<<dim3(NROWS * KD / 4 / 256), dim3(256), 0, stream>>>(
      (const float4*)F, (const float4*)M, (ushort4*)Fb, (ushort4*)Mb, sums);
  gemm_kernel<<<dim3(8, 64, 3), dim3(256), 0, stream>>>(Fb, Mb, sums);
  loss_kernel<<<dim3(1), dim3(1024), 0, stream>>>(sums, out);
}

// Round 5
// 82.701 us; speedup vs baseline: 3.2845x; 1.8327x over previous
//
#include <hip/hip_runtime.h>

#define NROWS 8192
#define KD    128
#define SQK1C 4.5398163f   /* sqrt(log2(e)/0.07); scaled ops make MFMA emit K1C*sim */

typedef __bf16 bf16x8 __attribute__((ext_vector_type(8)));
typedef float  f32x4  __attribute__((ext_vector_type(4)));

typedef __attribute__((address_space(1))) void* gas_ptr;
typedef __attribute__((address_space(3))) void* las_ptr;

__device__ __forceinline__ unsigned short f2bf(float x) {
  unsigned int u = __builtin_bit_cast(unsigned int, x);
  unsigned int r = (u + 0x7FFFu + ((u >> 16) & 1u)) >> 16;  // RNE
  return (unsigned short)r;
}

// fp32 -> bf16 scaled by sqrt(K1C); zero the 4 sum arrays.
__global__ __launch_bounds__(256) void prep_kernel(const float4* __restrict__ F4,
                                                   const float4* __restrict__ M4,
                                                   ushort4* __restrict__ Fb4,
                                                   ushort4* __restrict__ Mb4,
                                                   float* __restrict__ sums) {
  int i = blockIdx.x * 256 + threadIdx.x;
  float4 f = F4[i];
  float4 m = M4[i];
  ushort4 fo, mo;
  fo.x = f2bf(f.x * SQK1C); fo.y = f2bf(f.y * SQK1C);
  fo.z = f2bf(f.z * SQK1C); fo.w = f2bf(f.w * SQK1C);
  mo.x = f2bf(m.x * SQK1C); mo.y = f2bf(m.y * SQK1C);
  mo.z = f2bf(m.z * SQK1C); mo.w = f2bf(m.w * SQK1C);
  Fb4[i] = fo;
  Mb4[i] = mo;
  if (i < 4 * NROWS) sums[i] = 0.0f;
}

// z=0: FM (rowsum->Spos_f, colsum->Spos_m). z=1: FF (rowsum->Sneg_f, diag masked).
// z=2: MM (rowsum->Sneg_m, diag masked).
// 4 waves (2 wr x 2 wc). Block strip 128 rows x 1024 cols; 16 chunks of 64 cols.
// A (128x128) in regs per wave (64 rows, af=64 VGPR); B chunks double-buffered 2x16KB LDS.
// launch_bounds(256,3): VGPR cap 170 > ~140 need -> NO SPILL (round-4 lesson: cap 128 spilled af).
__global__ __launch_bounds__(256, 3) void gemm_kernel(const unsigned short* __restrict__ Fb,
                                                      const unsigned short* __restrict__ Mb,
                                                      float* __restrict__ sums) {
  __shared__ __align__(16) unsigned short lds[2][64 * KD];  // 2 x 16KB (A-stage borrows all 32KB)

  const int bx = blockIdx.x;   // 0..7   col strip (1024)
  const int by = blockIdx.y;   // 0..63  row block (128)
  const int z  = blockIdx.z;   // 0..2

  const unsigned short* A;
  const unsigned short* B;
  float* rowsum;
  float* colsum = nullptr;
  if (z == 0)      { A = Fb; B = Mb; rowsum = sums;             colsum = sums + NROWS; }
  else if (z == 1) { A = Fb; B = Fb; rowsum = sums + 2 * NROWS; }
  else             { A = Mb; B = Mb; rowsum = sums + 3 * NROWS; }

  const int tid  = threadIdx.x;
  const int lane = tid & 63;
  const int wave = tid >> 6;          // 0..3
  const int wr = wave >> 1, wc = wave & 1;
  const int l15 = lane & 15, l4 = lane >> 4;

  // Stage one 16KB B-chunk (64 rows x 256B). Linear LDS dest; source pre-XORed (rule 21).
  auto stageB = [&](void* dst, const unsigned short* src) {
    #pragma unroll
    for (int i = 0; i < 4; ++i) {
      const int lin = tid * 16 + i * 4096;
      const int row = lin >> 8;
      const int sbc = (lin & 255) ^ ((row & 7) << 4);
      __builtin_amdgcn_global_load_lds((gas_ptr)((const char*)src + row * 256 + sbc),
                                       (las_ptr)((char*)dst + lin), 16, 0, 0);
    }
  };

  // ---- A strip (32KB) through LDS into regs
  {
    const unsigned short* Abase = A + (size_t)by * 128 * KD;
    #pragma unroll
    for (int i = 0; i < 8; ++i) {
      const int lin = tid * 16 + i * 4096;
      const int row = lin >> 8;
      const int sbc = (lin & 255) ^ ((row & 7) << 4);
      __builtin_amdgcn_global_load_lds((gas_ptr)((const char*)Abase + row * 256 + sbc),
                                       (las_ptr)((char*)lds + lin), 16, 0, 0);
    }
  }
  __syncthreads();

  bf16x8 af[4][4];   // 64 rows x K128 per wave
  #pragma unroll
  for (int m = 0; m < 4; ++m) {
    const int row = wr * 64 + m * 16 + l15;
    const char* ab = (const char*)lds + row * 256;
    const int sw = (row & 7) << 4;
    #pragma unroll
    for (int k = 0; k < 4; ++k)
      af[m][k] = *(const bf16x8*)(ab + ((k * 64 + l4 * 16) ^ sw));
  }
  __syncthreads();   // all waves done with A before B chunk 0 overwrites

  float rowacc[16];
  #pragma unroll
  for (int i = 0; i < 16; ++i) rowacc[i] = 0.f;

  const unsigned short* Bbase = B + (size_t)bx * 1024 * KD;
  stageB(lds[0], Bbase);
  stageB(lds[1], Bbase + 64 * KD);
  __syncthreads();

  const int brow0 = wc * 32 + l15;          // n=0 B-row (out col); n=1 adds 16
  const int bsw   = (brow0 & 7) << 4;       // (brow0+16)&7 == brow0&7

  for (int t = 0; t < 16; ++t) {
    const char* bb = (const char*)lds[t & 1];
    const char* pb0 = bb + brow0 * 256;

    f32x4 acc[4][2] = {};
    __builtin_amdgcn_s_setprio(1);
    #pragma unroll
    for (int k = 0; k < 4; ++k) {
      const int c = (k * 64 + l4 * 16) ^ bsw;
      bf16x8 b0 = *(const bf16x8*)(pb0 + c);
      bf16x8 b1 = *(const bf16x8*)(pb0 + 16 * 256 + c);
      #pragma unroll
      for (int m = 0; m < 4; ++m) {
        acc[m][0] = __builtin_amdgcn_mfma_f32_16x16x32_bf16(af[m][k], b0, acc[m][0], 0, 0, 0);
        acc[m][1] = __builtin_amdgcn_mfma_f32_16x16x32_bf16(af[m][k], b1, acc[m][1], 0, 0, 0);
      }
    }
    __builtin_amdgcn_s_setprio(0);

    // Epilogue: v = exp2(K1C*sim); rowacc in regs; colsum (z==0) lane-local + atomic.
    const bool diag = (z > 0) && ((((bx << 4) + t) >> 1) == by);
    if (z == 0) {
      float ca0 = 0.f, ca1 = 0.f;
      #pragma unroll
      for (int m = 0; m < 4; ++m) {
        #pragma unroll
        for (int j = 0; j < 4; ++j) {
          float v0 = __builtin_amdgcn_exp2f(acc[m][0][j]);
          float v1 = __builtin_amdgcn_exp2f(acc[m][1][j]);
          rowacc[m * 4 + j] += v0 + v1;
          ca0 += v0; ca1 += v1;
        }
      }
      ca0 += __shfl_xor(ca0, 16);
      ca0 += __shfl_xor(ca0, 32);
      ca1 += __shfl_xor(ca1, 16);
      ca1 += __shfl_xor(ca1, 32);
      if (l4 == 0) {
        float* cp = colsum + bx * 1024 + t * 64 + wc * 32 + l15;
        unsafeAtomicAdd(cp, ca0);
        unsafeAtomicAdd(cp + 16, ca1);
      }
    } else {
      #pragma unroll
      for (int m = 0; m < 4; ++m) {
        #pragma unroll
        for (int j = 0; j < 4; ++j) {
          float v0 = __builtin_amdgcn_exp2f(acc[m][0][j]);
          float v1 = __builtin_amdgcn_exp2f(acc[m][1][j]);
          if (diag) {
            const int grow = by * 128 + wr * 64 + m * 16 + l4 * 4 + j;
            const int gcol = bx * 1024 + t * 64 + wc * 32 + l15;
            if (grow == gcol)      v0 = 0.f;
            if (grow == gcol + 16) v1 = 0.f;
          }
          rowacc[m * 4 + j] += v0 + v1;
        }
      }
    }
    __syncthreads();                    // drains vmcnt+lgkm; buffer t&1 free to re-stage
    if (t < 14) stageB(lds[t & 1], Bbase + (size_t)(t + 2) * 64 * KD);
  }

  // rowsum flush: butterfly over l15 (cols), 4 lanes/wave do the atomics.
  #pragma unroll
  for (int i = 0; i < 16; ++i) {
    float v = rowacc[i];
    v += __shfl_xor(v, 1);
    v += __shfl_xor(v, 2);
    v += __shfl_xor(v, 4);
    v += __shfl_xor(v, 8);
    rowacc[i] = v;
  }
  if (l15 == 0) {
    const int rbase = by * 128 + wr * 64 + l4 * 4;
    #pragma unroll
    for (int i = 0; i < 16; ++i)
      unsafeAtomicAdd(rowsum + rbase + (i >> 2) * 16 + (i & 3), rowacc[i]);
  }
}

// loss = 1.5*mean(log1p(Sneg_f/Spos_f)) + 0.5*mean(log1p(Sneg_m/Spos_m))
// (uniform 2^{-K1C} factor cancels in the ratios)
__global__ __launch_bounds__(1024) void loss_kernel(const float* __restrict__ sums,
                                                    float* __restrict__ out) {
  const float* Spf = sums;
  const float* Spm = sums + NROWS;
  const float* Snf = sums + 2 * NROWS;
  const float* Snm = sums + 3 * NROWS;
  float accf = 0.f, accm = 0.f;
  for (int i = threadIdx.x; i < NROWS; i += 1024) {
    accf += log1pf(Snf[i] / Spf[i]);
    accm += log1pf(Snm[i] / Spm[i]);
  }
  float v = 1.5f * accf + 0.5f * accm;
  #pragma unroll
  for (int s = 1; s < 64; s <<= 1) v += __shfl_xor(v, s);
  __shared__ float red[16];
  if ((threadIdx.x & 63) == 0) red[threadIdx.x >> 6] = v;
  __syncthreads();
  if (threadIdx.x == 0) {
    float s = 0.f;
    #pragma unroll
    for (int i = 0; i < 16; ++i) s += red[i];
    out[0] = s * (1.0f / NROWS);
  }
}

extern "C" void kernel_launch(void* const* d_in, const int* in_sizes, int n_in,
                              void* d_out, int out_size, void* d_ws, size_t ws_size,
                              hipStream_t stream) {
  (void)in_sizes; (void)n_in; (void)out_size; (void)ws_size;
  const float* F = (const float*)d_in[0];
  const float* M = (const float*)d_in[1];
  float* out = (float*)d_out;

  float* sums = (float*)d_ws;
  unsigned short* Fb = (unsigned short*)((char*)d_ws + 4 * NROWS * sizeof(float));
  unsigned short* Mb = Fb + (size_t)NROWS * KD;

  prep_kernel<<<dim3(NROWS * KD / 4 / 256), dim3(256), 0, stream>>>(
      (const float4*)F, (const float4*)M, (ushort4*)Fb, (ushort4*)Mb, sums);
  gemm_kernel<<<dim3(8, 64, 3), dim3(256), 0, stream>>>(Fb, Mb, sums);
  loss_kernel<<<dim3(1), dim3(1024), 0, stream>>>(sums, out);
}